// Round 6
// baseline (1160.865 us; speedup 1.0000x reference)
//
// SelfAttentionWide (B=4, T=1024, E=512, H=8 wide heads) — MI355X gfx950
// Round 6: fix flash register spills. R5 evidence: flash WRITE_SIZE=650MB vs 32MB
// of legitimate stores + FETCH 436MB = scratch spill traffic (oacc[2][16]=128 VGPRs
// + sacc/tmp/qf > 230 live regs vs 128 allocated). Now Br=32 rows/block: oacc[2][8]
// = 64 regs, 4 waves own 32-col slices (4-way cross-wave softmax exchange in LDS).
// Grid 32x32 pair-swizzled. Everything outside flash_kernel unchanged from R5.
#include <hip/hip_runtime.h>
#include <stdint.h>

typedef unsigned short u16;
typedef unsigned int u32;
typedef __bf16 bf16_t;
typedef __attribute__((ext_vector_type(8))) bf16_t bf16x8;
typedef __attribute__((ext_vector_type(4))) float floatx4;

__device__ __forceinline__ u16 f2b(float f) {
  u32 u = __float_as_uint(f);
  return (u16)((u + 0x7fffu + ((u >> 16) & 1u)) >> 16);
}

// async 16B/lane global->LDS; LDS dest is wave-uniform base + lane*16
__device__ __forceinline__ void gload_lds16(const u16* g, u16* l) {
  __builtin_amdgcn_global_load_lds(
      (const __attribute__((address_space(1))) u32*)g,
      (__attribute__((address_space(3))) u32*)l, 16, 0, 0);
}

// fused fp32 -> bf16: blockIdx.y selects tensor (all 2M elements)
__global__ __launch_bounds__(256) void cvt_kernel(
    const float* __restrict__ s0, const float* __restrict__ s1,
    const float* __restrict__ s2, const float* __restrict__ s3,
    const float* __restrict__ s4, u16* __restrict__ dbase) {
  const int which = blockIdx.y;
  const float* s = which == 0 ? s0 : which == 1 ? s1 : which == 2 ? s2
                 : which == 3 ? s3 : s4;
  u16* d = dbase + (long)which * 2097152;
  const int i = blockIdx.x * 256 + threadIdx.x;
  const float4 v = ((const float4*)s)[i];
  ushort4 o;
  o.x = f2b(v.x); o.y = f2b(v.y); o.z = f2b(v.z); o.w = f2b(v.w);
  ((ushort4*)d)[i] = o;
}

// out[4096 x 512] fp32 <- broadcast bias rows (pre-pass for split-K atomic unify)
__global__ __launch_bounds__(256) void init_out_kernel(float* __restrict__ out,
                                                       const float* __restrict__ bias) {
  const int i = blockIdx.x * 256 + threadIdx.x;  // 524288 float4s
  const int c4 = i & 127;
  ((float4*)out)[i] = ((const float4*)bias)[c4];
}

enum { A_PLAIN = 0, A_HEADBLK = 1 };   // HEADBLK: A is O in (b,h,t,e), logical (r=(b,t), k=(h,e))
enum { C_BF16_BHTE = 1, C_F32_ATOMIC = 3, C_BF16_BHET = 4 };

// C[M x N] = A[M x K] @ B[N x K]^T  (bf16 in, fp32 acc), tile 128x128x32,
// 256 thr = 4 waves (2x2), wave = 4x4 of 16x16x32 MFMA.
// SPLITK: blockIdx.z selects a K-chunk of size K (param = chunk), epilogue atomics.
template <int AMODE, int CMODE, bool SPLITK>
__global__ __launch_bounds__(256, 2) void gemm_kernel(
    const u16* __restrict__ A, int lda,
    const u16* __restrict__ B, int ldb, long b_zstride,
    void* __restrict__ C, int ldc, long c_zstride,
    int K, float scale) {
  const int bn = blockIdx.x, bm = blockIdx.y, bz = blockIdx.z;

  const int kTiles = K >> 5;
  const int kbase = SPLITK ? bz * K : 0;

  const u16* Ab = A;
  const u16* Bb = B + (SPLITK ? 0 : (long)bz * b_zstride);

  __shared__ u16 sA[128 * 32];
  __shared__ u16 sB[128 * 32];

  const int tid = threadIdx.x;
  const int wid = tid >> 6;
  const int lane = tid & 63;
  const int lrow = lane & 15;
  const int quad = lane >> 4;
  const int wm = wid >> 1, wn = wid & 1;
  const int m0 = bm * 128, n0 = bn * 128;

  const int sgr = lane >> 2;        // staging row within 16-row chunk
  const int sgc = (lane & 3) << 3;  // staging col (8 bf16 = 16B)

  floatx4 acc[4][4];
#pragma unroll
  for (int i = 0; i < 4; ++i)
#pragma unroll
    for (int j = 0; j < 4; ++j) acc[i][j] = (floatx4)0.0f;

  for (int kt = 0; kt < kTiles; ++kt) {
    const int k0 = kbase + (kt << 5);
#pragma unroll
    for (int j = 0; j < 2; ++j) {
      const int r = wid * 32 + j * 16 + sgr;
      const u16* g;
      if constexpr (AMODE == A_PLAIN) {
        g = Ab + (long)(m0 + r) * lda + (k0 + sgc);
      } else {
        const int rg = m0 + r, kg = k0 + sgc;
        g = Ab + (long)((rg >> 10) * 8 + (kg >> 9)) * 524288 +
            (long)(rg & 1023) * 512 + (kg & 511);
      }
      gload_lds16(g, &sA[(wid * 32 + j * 16) * 32]);
    }
#pragma unroll
    for (int j = 0; j < 2; ++j) {
      const int r = wid * 32 + j * 16 + sgr;
      const u16* g = Bb + (long)(n0 + r) * ldb + (k0 + sgc);
      gload_lds16(g, &sB[(wid * 32 + j * 16) * 32]);
    }
    __syncthreads();

    bf16x8 af[4], bfr[4];
#pragma unroll
    for (int i = 0; i < 4; ++i)
      af[i] = *(const bf16x8*)&sA[(wm * 64 + i * 16 + lrow) * 32 + (quad << 3)];
#pragma unroll
    for (int i = 0; i < 4; ++i)
      bfr[i] = *(const bf16x8*)&sB[(wn * 64 + i * 16 + lrow) * 32 + (quad << 3)];
#pragma unroll
    for (int mi = 0; mi < 4; ++mi)
#pragma unroll
      for (int ni = 0; ni < 4; ++ni)
        acc[mi][ni] = __builtin_amdgcn_mfma_f32_16x16x32_bf16(af[mi], bfr[ni], acc[mi][ni], 0, 0, 0);
    __syncthreads();
  }

  // ---- epilogue: D[row=(quad*4+r)][col=lrow] per 16x16 tile (m89-verified layout)
#pragma unroll
  for (int mi = 0; mi < 4; ++mi) {
#pragma unroll
    for (int ni = 0; ni < 4; ++ni) {
      const int cg = n0 + wn * 64 + ni * 16 + lrow;
      if constexpr (CMODE == C_BF16_BHET) {
        // V transposed: (b,h,e,t); 4 consecutive t per lane -> one ushort4
        const int rgb = m0 + wm * 64 + mi * 16 + quad * 4;
        const long idx = (long)((rgb >> 10) * 8 + (cg >> 9)) * 524288 +
                         (long)(cg & 511) * 1024 + (rgb & 1023);
        ushort4 o;
        o.x = f2b(acc[mi][ni][0]); o.y = f2b(acc[mi][ni][1]);
        o.z = f2b(acc[mi][ni][2]); o.w = f2b(acc[mi][ni][3]);
        *(ushort4*)&((u16*)C)[idx] = o;
      } else {
#pragma unroll
        for (int r = 0; r < 4; ++r) {
          const int rg = m0 + wm * 64 + mi * 16 + quad * 4 + r;
          const float val = acc[mi][ni][r] * scale;
          if constexpr (CMODE == C_F32_ATOMIC) {
            atomicAdd(&((float*)C)[(long)rg * ldc + cg], val);
          } else {  // C_BF16_BHTE: (r=(b,t), c=(h,e)) -> (b,h,t,e), + z offset
            const long idx = (long)bz * c_zstride +
                             (long)((rg >> 10) * 8 + (cg >> 9)) * 524288 +
                             (long)(rg & 1023) * 512 + (cg & 511);
            ((u16*)C)[idx] = f2b(val);
          }
        }
      }
    }
  }
}

// Flash attention: one block = 32 Q-rows of one (b,h). Q,K (b,h,t,e); VT (b,h,e,t);
// O (b,h,t,e). 4 waves each own a 32-col slice (of the 128-col S tile, and of each
// 128-e output chunk). Online softmax with 4-way cross-wave LDS exchange.
__global__ __launch_bounds__(256, 2) void flash_kernel(
    const u16* __restrict__ Q, const u16* __restrict__ K,
    const u16* __restrict__ VT, u16* __restrict__ O, float s2) {
  const int bx = blockIdx.x;
  const int bm = (bx & 1) ? (31 - (bx >> 1)) : (bx >> 1);  // pair-swizzle: balance triangle
  const int bh = blockIdx.y;
  const long base = (long)bh * 524288;
  const int tid = threadIdx.x;
  const int lane = tid & 63;
  const int w = tid >> 6;   // wave id = col-slice owner
  const int g = lane >> 4;
  const int l15 = lane & 15;

  __shared__ u16 sU[128 * 136];   // K-chunk [t=128][e:128] / V-chunk [e=128][t:128], pad 8
  __shared__ u16 sP[32 * 136];    // P [row=32][col=128], pad 8
  __shared__ float sredm[4][32];  // per-wave partial row max
  __shared__ float sreds[4][32];  // per-wave partial row sum

  floatx4 oacc[2][8];  // [rt][ech*2+ci]: row bm*32+rt*16+g*4+r, col ech*128+w*32+ci*16+l15
#pragma unroll
  for (int a = 0; a < 2; ++a)
#pragma unroll
    for (int b = 0; b < 8; ++b) oacc[a][b] = (floatx4)0.0f;
  float m_r[2][4], l_r[2][4];
#pragma unroll
  for (int a = 0; a < 2; ++a)
#pragma unroll
    for (int r = 0; r < 4; ++r) { m_r[a][r] = -1e30f; l_r[a][r] = 0.0f; }

  const int srow = tid >> 1;          // staging row (0..127)
  const int shalf = (tid & 1) * 64;   // staging col half (u16 units)
  u16* sdst = &sU[srow * 136 + shalf];

  const int nkt = (bm >> 2) + 1;
  for (int kt = 0; kt < nkt; ++kt) {
    // ================= Phase A: S = s2 * Q Kt^T (32x128), contraction e chunked by 128
    floatx4 sacc[2][2];
#pragma unroll
    for (int a = 0; a < 2; ++a)
#pragma unroll
      for (int b = 0; b < 2; ++b) sacc[a][b] = (floatx4)0.0f;

    for (int ec = 0; ec < 4; ++ec) {
      const u16* kg = K + base + (long)(kt * 128 + srow) * 512 + ec * 128 + shalf;
      uint4 tmp[8];
#pragma unroll
      for (int c = 0; c < 8; ++c) tmp[c] = ((const uint4*)kg)[c];
      __syncthreads();  // prior chunk's frag reads done
#pragma unroll
      for (int c = 0; c < 8; ++c) *(uint4*)(sdst + c * 8) = tmp[c];
      // Q frags (global, L2-resident): rows bm*32+rt*16+l15, col ec*128+s*32+g*8
      bf16x8 qf[2][4];
#pragma unroll
      for (int rt = 0; rt < 2; ++rt)
#pragma unroll
        for (int s = 0; s < 4; ++s)
          qf[rt][s] = *(const bf16x8*)(Q + base +
              (long)(bm * 32 + rt * 16 + l15) * 512 + ec * 128 + s * 32 + g * 8);
      __syncthreads();
#pragma unroll
      for (int ci = 0; ci < 2; ++ci) {
#pragma unroll
        for (int s = 0; s < 4; ++s) {
          const bf16x8 kf = *(const bf16x8*)&sU[(w * 32 + ci * 16 + l15) * 136 + s * 32 + g * 8];
#pragma unroll
          for (int rt = 0; rt < 2; ++rt)
            sacc[rt][ci] = __builtin_amdgcn_mfma_f32_16x16x32_bf16(qf[rt][s], kf, sacc[rt][ci], 0, 0, 0);
        }
      }
    }

    // scale + causal mask (only the diagonal kt is partial)
    const bool diag = (kt == (bm >> 2));
#pragma unroll
    for (int rt = 0; rt < 2; ++rt)
#pragma unroll
      for (int ci = 0; ci < 2; ++ci)
#pragma unroll
        for (int r = 0; r < 4; ++r) {
          float v = sacc[rt][ci][r] * s2;
          if (diag) {
            const int col = kt * 128 + w * 32 + ci * 16 + l15;
            const int row = bm * 32 + rt * 16 + g * 4 + r;
            v = (col > row) ? -1e30f : v;
          }
          sacc[rt][ci][r] = v;
        }

    // ---- online softmax; rows span all 4 waves -> LDS exchange of partials
    float tm[2][4], alpha[2][4];
#pragma unroll
    for (int rt = 0; rt < 2; ++rt)
#pragma unroll
      for (int r = 0; r < 4; ++r) {
        tm[rt][r] = fmaxf(sacc[rt][0][r], sacc[rt][1][r]);
#pragma unroll
        for (int off = 1; off <= 8; off <<= 1) tm[rt][r] = fmaxf(tm[rt][r], __shfl_xor(tm[rt][r], off));
        if (l15 == 0) sredm[w][rt * 16 + g * 4 + r] = tm[rt][r];
      }
    __syncthreads();  // partial maxes visible
#pragma unroll
    for (int rt = 0; rt < 2; ++rt)
#pragma unroll
      for (int r = 0; r < 4; ++r) {
        const int row = rt * 16 + g * 4 + r;
        const float m4 = fmaxf(fmaxf(sredm[0][row], sredm[1][row]),
                               fmaxf(sredm[2][row], sredm[3][row]));
        const float mnew = fmaxf(m_r[rt][r], m4);
        alpha[rt][r] = __expf(m_r[rt][r] - mnew);
        m_r[rt][r] = mnew;
        const float p0 = __expf(sacc[rt][0][r] - mnew);
        const float p1 = __expf(sacc[rt][1][r] - mnew);
        sacc[rt][0][r] = p0; sacc[rt][1][r] = p1;
        float s = p0 + p1;
#pragma unroll
        for (int off = 1; off <= 8; off <<= 1) s += __shfl_xor(s, off);
        if (l15 == 0) sreds[w][row] = s;
      }
    __syncthreads();  // partial sums visible
#pragma unroll
    for (int rt = 0; rt < 2; ++rt) {
#pragma unroll
      for (int r = 0; r < 4; ++r) {
        const int row = rt * 16 + g * 4 + r;
        const float s4 = (sreds[0][row] + sreds[1][row]) + (sreds[2][row] + sreds[3][row]);
        l_r[rt][r] = l_r[rt][r] * alpha[rt][r] + s4;
      }
      // rescale O accumulator
#pragma unroll
      for (int t = 0; t < 8; ++t)
#pragma unroll
        for (int r = 0; r < 4; ++r) oacc[rt][t][r] *= alpha[rt][r];
      // write P (bf16) to LDS: row rt*16+g*4+r, col w*32+ci*16+l15
#pragma unroll
      for (int ci = 0; ci < 2; ++ci)
#pragma unroll
        for (int r = 0; r < 4; ++r)
          sP[(rt * 16 + g * 4 + r) * 136 + w * 32 + ci * 16 + l15] = f2b(sacc[rt][ci][r]);
    }

    // ================= Phase B: O += P @ V (32x512), output e chunked by 128
    for (int ech = 0; ech < 4; ++ech) {
      const u16* vg = VT + base + (long)(ech * 128 + srow) * 1024 + kt * 128 + shalf;
      uint4 tmp[8];
#pragma unroll
      for (int c = 0; c < 8; ++c) tmp[c] = ((const uint4*)vg)[c];
      __syncthreads();  // Phase A frag reads + sP writes done (ech0); prior vf reads (1..3)
#pragma unroll
      for (int c = 0; c < 8; ++c) *(uint4*)(sdst + c * 8) = tmp[c];
      __syncthreads();
      // P A-frags: row rt*16+l15, k = ks*32+g*8
      bf16x8 pf[2][4];
#pragma unroll
      for (int rt = 0; rt < 2; ++rt)
#pragma unroll
        for (int ks = 0; ks < 4; ++ks)
          pf[rt][ks] = *(const bf16x8*)&sP[(rt * 16 + l15) * 136 + ks * 32 + g * 8];
#pragma unroll
      for (int ci = 0; ci < 2; ++ci) {
#pragma unroll
        for (int ks = 0; ks < 4; ++ks) {
          const bf16x8 vf = *(const bf16x8*)&sU[(w * 32 + ci * 16 + l15) * 136 + ks * 32 + g * 8];
#pragma unroll
          for (int rt = 0; rt < 2; ++rt)
            oacc[rt][ech * 2 + ci] =
                __builtin_amdgcn_mfma_f32_16x16x32_bf16(pf[rt][ks], vf, oacc[rt][ech * 2 + ci], 0, 0, 0);
        }
      }
    }
    __syncthreads();  // vf reads done before next kt's Phase A staging
  }

  // ---- epilogue: O = oacc / l, write (b,h,t,e) bf16
#pragma unroll
  for (int rt = 0; rt < 2; ++rt) {
    float inv[4];
#pragma unroll
    for (int r = 0; r < 4; ++r) inv[r] = 1.0f / l_r[rt][r];
#pragma unroll
    for (int t = 0; t < 8; ++t) {
      const int col = (t >> 1) * 128 + w * 32 + (t & 1) * 16 + l15;
#pragma unroll
      for (int r = 0; r < 4; ++r) {
        const int row = bm * 32 + rt * 16 + g * 4 + r;
        O[base + (long)row * 512 + col] = f2b(oacc[rt][t][r] * inv[r]);
      }
    }
  }
}

extern "C" void kernel_launch(void* const* d_in, const int* in_sizes, int n_in,
                              void* d_out, int out_size, void* d_ws, size_t ws_size,
                              hipStream_t stream) {
  const float* x   = (const float*)d_in[0];
  const float* w_k = (const float*)d_in[1];
  const float* w_q = (const float*)d_in[2];
  const float* w_v = (const float*)d_in[3];
  const float* w_u = (const float*)d_in[4];
  const float* b_u = (const float*)d_in[5];
  float* out = (float*)d_out;
  char* ws = (char*)d_ws;

  const long MB = 1048576;
  // ws: xb 0, wqb 4, wkb 8, wvb 12, wub 16 (bf16); Q 20..52, K 52..84, VT 84..116, O 116..148
  u16* xb  = (u16*)(ws);
  u16* wqb = (u16*)(ws + 4 * MB);
  u16* wvb = (u16*)(ws + 12 * MB);
  u16* wub = (u16*)(ws + 16 * MB);
  u16* Q   = (u16*)(ws + 20 * MB);
  u16* Kb  = (u16*)(ws + 52 * MB);
  u16* VT  = (u16*)(ws + 84 * MB);
  u16* O   = (u16*)(ws + 116 * MB);

  const dim3 blk(256);
  const float s2 = 0.044194173824159216f;  // 512^{-1/2} == (e^{-1/4})^2 folded into scores

  // fused fp32 -> bf16 conversions: dest order matches ws layout (x,q,k,v,u)
  cvt_kernel<<<dim3(2048, 5), blk, 0, stream>>>(x, w_q, w_k, w_v, w_u, xb);

  // Q,K projections fused (z in {q,k}) -> (b,h,t,e)
  gemm_kernel<A_PLAIN, C_BF16_BHTE, false>
      <<<dim3(32, 32, 2), blk, 0, stream>>>(xb, 512, wqb, 512, 2097152,
                                            Q, 0, 16777216, 512, 1.0f);
  // V projection -> transposed (b,h,e,t)
  gemm_kernel<A_PLAIN, C_BF16_BHET, false>
      <<<dim3(32, 32, 1), blk, 0, stream>>>(xb, 512, wvb, 512, 0,
                                            VT, 0, 0, 512, 1.0f);

  // flash attention: 32 Q-tiles (32 rows each) x 32 (b,h)
  flash_kernel<<<dim3(32, 32), blk, 0, stream>>>(Q, Kb, VT, O, s2);

  // unify: out(fp32) = O2d @ w_u^T + b_u, split-K x4 (chunk 1024), atomics over bias-init
  init_out_kernel<<<2048, blk, 0, stream>>>(out, b_u);
  gemm_kernel<A_HEADBLK, C_F32_ATOMIC, true>
      <<<dim3(4, 32, 4), blk, 0, stream>>>(O, 0, wub, 4096, 0, out, 512, 0, 1024, 1.0f);
}

// Round 7
// 553.870 us; speedup vs baseline: 2.0959x; 2.0959x over previous
//
// SelfAttentionWide (B=4, T=1024, E=512, H=8 wide heads) — MI355X gfx950
// Round 7: kill flash spills for real. R5/R6 both pinned at VGPR_Count=128 with
// ~1GB scratch WRITE traffic -> launch_bounds(256,2) capped the unified RF at 128
// and oacc spilled. Now: (a) __launch_bounds__(256,1) -> 512-reg cap; (b) K/V staged
// via async global_load_lds into XOR-swizzled LDS (group^=row&15) -- no tmp regs,
// conflict-free b128 frag reads, wave-local rows; (c) Phase-A qf shrunk 32->8 regs
// (loop over k-slice). Everything outside flash_kernel unchanged from R6.
#include <hip/hip_runtime.h>
#include <stdint.h>

typedef unsigned short u16;
typedef unsigned int u32;
typedef __bf16 bf16_t;
typedef __attribute__((ext_vector_type(8))) bf16_t bf16x8;
typedef __attribute__((ext_vector_type(4))) float floatx4;

__device__ __forceinline__ u16 f2b(float f) {
  u32 u = __float_as_uint(f);
  return (u16)((u + 0x7fffu + ((u >> 16) & 1u)) >> 16);
}

// async 16B/lane global->LDS; LDS dest is wave-uniform base + lane*16
__device__ __forceinline__ void gload_lds16(const u16* g, u16* l) {
  __builtin_amdgcn_global_load_lds(
      (const __attribute__((address_space(1))) u32*)g,
      (__attribute__((address_space(3))) u32*)l, 16, 0, 0);
}

// fused fp32 -> bf16: blockIdx.y selects tensor (all 2M elements)
__global__ __launch_bounds__(256) void cvt_kernel(
    const float* __restrict__ s0, const float* __restrict__ s1,
    const float* __restrict__ s2, const float* __restrict__ s3,
    const float* __restrict__ s4, u16* __restrict__ dbase) {
  const int which = blockIdx.y;
  const float* s = which == 0 ? s0 : which == 1 ? s1 : which == 2 ? s2
                 : which == 3 ? s3 : s4;
  u16* d = dbase + (long)which * 2097152;
  const int i = blockIdx.x * 256 + threadIdx.x;
  const float4 v = ((const float4*)s)[i];
  ushort4 o;
  o.x = f2b(v.x); o.y = f2b(v.y); o.z = f2b(v.z); o.w = f2b(v.w);
  ((ushort4*)d)[i] = o;
}

// out[4096 x 512] fp32 <- broadcast bias rows (pre-pass for split-K atomic unify)
__global__ __launch_bounds__(256) void init_out_kernel(float* __restrict__ out,
                                                       const float* __restrict__ bias) {
  const int i = blockIdx.x * 256 + threadIdx.x;  // 524288 float4s
  const int c4 = i & 127;
  ((float4*)out)[i] = ((const float4*)bias)[c4];
}

enum { A_PLAIN = 0, A_HEADBLK = 1 };   // HEADBLK: A is O in (b,h,t,e), logical (r=(b,t), k=(h,e))
enum { C_BF16_BHTE = 1, C_F32_ATOMIC = 3, C_BF16_BHET = 4 };

// C[M x N] = A[M x K] @ B[N x K]^T  (bf16 in, fp32 acc), tile 128x128x32,
// 256 thr = 4 waves (2x2), wave = 4x4 of 16x16x32 MFMA.
// SPLITK: blockIdx.z selects a K-chunk of size K (param = chunk), epilogue atomics.
template <int AMODE, int CMODE, bool SPLITK>
__global__ __launch_bounds__(256, 2) void gemm_kernel(
    const u16* __restrict__ A, int lda,
    const u16* __restrict__ B, int ldb, long b_zstride,
    void* __restrict__ C, int ldc, long c_zstride,
    int K, float scale) {
  const int bn = blockIdx.x, bm = blockIdx.y, bz = blockIdx.z;

  const int kTiles = K >> 5;
  const int kbase = SPLITK ? bz * K : 0;

  const u16* Ab = A;
  const u16* Bb = B + (SPLITK ? 0 : (long)bz * b_zstride);

  __shared__ u16 sA[128 * 32];
  __shared__ u16 sB[128 * 32];

  const int tid = threadIdx.x;
  const int wid = tid >> 6;
  const int lane = tid & 63;
  const int lrow = lane & 15;
  const int quad = lane >> 4;
  const int wm = wid >> 1, wn = wid & 1;
  const int m0 = bm * 128, n0 = bn * 128;

  const int sgr = lane >> 2;        // staging row within 16-row chunk
  const int sgc = (lane & 3) << 3;  // staging col (8 bf16 = 16B)

  floatx4 acc[4][4];
#pragma unroll
  for (int i = 0; i < 4; ++i)
#pragma unroll
    for (int j = 0; j < 4; ++j) acc[i][j] = (floatx4)0.0f;

  for (int kt = 0; kt < kTiles; ++kt) {
    const int k0 = kbase + (kt << 5);
#pragma unroll
    for (int j = 0; j < 2; ++j) {
      const int r = wid * 32 + j * 16 + sgr;
      const u16* g;
      if constexpr (AMODE == A_PLAIN) {
        g = Ab + (long)(m0 + r) * lda + (k0 + sgc);
      } else {
        const int rg = m0 + r, kg = k0 + sgc;
        g = Ab + (long)((rg >> 10) * 8 + (kg >> 9)) * 524288 +
            (long)(rg & 1023) * 512 + (kg & 511);
      }
      gload_lds16(g, &sA[(wid * 32 + j * 16) * 32]);
    }
#pragma unroll
    for (int j = 0; j < 2; ++j) {
      const int r = wid * 32 + j * 16 + sgr;
      const u16* g = Bb + (long)(n0 + r) * ldb + (k0 + sgc);
      gload_lds16(g, &sB[(wid * 32 + j * 16) * 32]);
    }
    __syncthreads();

    bf16x8 af[4], bfr[4];
#pragma unroll
    for (int i = 0; i < 4; ++i)
      af[i] = *(const bf16x8*)&sA[(wm * 64 + i * 16 + lrow) * 32 + (quad << 3)];
#pragma unroll
    for (int i = 0; i < 4; ++i)
      bfr[i] = *(const bf16x8*)&sB[(wn * 64 + i * 16 + lrow) * 32 + (quad << 3)];
#pragma unroll
    for (int mi = 0; mi < 4; ++mi)
#pragma unroll
      for (int ni = 0; ni < 4; ++ni)
        acc[mi][ni] = __builtin_amdgcn_mfma_f32_16x16x32_bf16(af[mi], bfr[ni], acc[mi][ni], 0, 0, 0);
    __syncthreads();
  }

  // ---- epilogue: D[row=(quad*4+r)][col=lrow] per 16x16 tile (m89-verified layout)
#pragma unroll
  for (int mi = 0; mi < 4; ++mi) {
#pragma unroll
    for (int ni = 0; ni < 4; ++ni) {
      const int cg = n0 + wn * 64 + ni * 16 + lrow;
      if constexpr (CMODE == C_BF16_BHET) {
        // V transposed: (b,h,e,t); 4 consecutive t per lane -> one ushort4
        const int rgb = m0 + wm * 64 + mi * 16 + quad * 4;
        const long idx = (long)((rgb >> 10) * 8 + (cg >> 9)) * 524288 +
                         (long)(cg & 511) * 1024 + (rgb & 1023);
        ushort4 o;
        o.x = f2b(acc[mi][ni][0]); o.y = f2b(acc[mi][ni][1]);
        o.z = f2b(acc[mi][ni][2]); o.w = f2b(acc[mi][ni][3]);
        *(ushort4*)&((u16*)C)[idx] = o;
      } else {
#pragma unroll
        for (int r = 0; r < 4; ++r) {
          const int rg = m0 + wm * 64 + mi * 16 + quad * 4 + r;
          const float val = acc[mi][ni][r] * scale;
          if constexpr (CMODE == C_F32_ATOMIC) {
            atomicAdd(&((float*)C)[(long)rg * ldc + cg], val);
          } else {  // C_BF16_BHTE: (r=(b,t), c=(h,e)) -> (b,h,t,e), + z offset
            const long idx = (long)bz * c_zstride +
                             (long)((rg >> 10) * 8 + (cg >> 9)) * 524288 +
                             (long)(rg & 1023) * 512 + (cg & 511);
            ((u16*)C)[idx] = f2b(val);
          }
        }
      }
    }
  }
}

// Flash attention: one block = 32 Q-rows of one (b,h). Q,K (b,h,t,e); VT (b,h,e,t);
// O (b,h,t,e). 4 waves own 32-col slices. K/V staged by async global_load_lds into
// an XOR-swizzled 128x128 LDS tile (group' = group ^ (row&15)): satisfies the
// uniform-base+lane*16 DMA constraint AND makes b128 frag reads conflict-free
// (frag row%16 == l15 -> 16 distinct groups). Staged rows are wave-local.
__global__ __launch_bounds__(256, 1) void flash_kernel(
    const u16* __restrict__ Q, const u16* __restrict__ K,
    const u16* __restrict__ VT, u16* __restrict__ O, float s2) {
  const int bx = blockIdx.x;
  const int bm = (bx & 1) ? (31 - (bx >> 1)) : (bx >> 1);  // pair-swizzle: balance triangle
  const int bh = blockIdx.y;
  const long base = (long)bh * 524288;
  const int tid = threadIdx.x;
  const int lane = tid & 63;
  const int w = tid >> 6;   // wave id = col-slice owner
  const int g = lane >> 4;
  const int l15 = lane & 15;

  __shared__ u16 sU[128 * 128];   // swizzled K/V tile (32 KB)
  __shared__ u16 sP[32 * 136];    // P [row=32][col=128], pad 8
  __shared__ float sredm[4][32];  // per-wave partial row max
  __shared__ float sreds[4][32];  // per-wave partial row sum

  floatx4 oacc[2][8];  // [rt][ech*2+ci]: row bm*32+rt*16+g*4+r, col ech*128+w*32+ci*16+l15
#pragma unroll
  for (int a = 0; a < 2; ++a)
#pragma unroll
    for (int b = 0; b < 8; ++b) oacc[a][b] = (floatx4)0.0f;
  float m_r[2][4], l_r[2][4];
#pragma unroll
  for (int a = 0; a < 2; ++a)
#pragma unroll
    for (int r = 0; r < 4; ++r) { m_r[a][r] = -1e30f; l_r[a][r] = 0.0f; }

  const int nkt = (bm >> 2) + 1;
  for (int kt = 0; kt < nkt; ++kt) {
    // ================= Phase A: S = s2 * Q Kt^T (32x128), contraction e chunked by 128
    floatx4 sacc[2][2];
#pragma unroll
    for (int a = 0; a < 2; ++a)
#pragma unroll
      for (int b = 0; b < 2; ++b) sacc[a][b] = (floatx4)0.0f;

    for (int ec = 0; ec < 4; ++ec) {
      __syncthreads();  // prior consumers of sU done
      // stage K rows [kt*128,+128) x e-cols [ec*128,+128); wave w: rows 32w..32w+31
#pragma unroll
      for (int j = 0; j < 8; ++j) {
        const int c = w * 8 + j;
        const int r = c * 4 + g;  // this lane's row
        const u16* gsrc = K + base + (long)(kt * 128 + r) * 512 + ec * 128 +
                          ((l15 ^ (r & 15)) << 3);
        gload_lds16(gsrc, &sU[c * 512]);
      }
      __syncthreads();  // DMA landed
#pragma unroll
      for (int s = 0; s < 4; ++s) {
        const bf16x8 qf0 = *(const bf16x8*)(Q + base +
            (long)(bm * 32 + l15) * 512 + ec * 128 + s * 32 + g * 8);
        const bf16x8 qf1 = *(const bf16x8*)(Q + base +
            (long)(bm * 32 + 16 + l15) * 512 + ec * 128 + s * 32 + g * 8);
#pragma unroll
        for (int ci = 0; ci < 2; ++ci) {
          const bf16x8 kf = *(const bf16x8*)&sU[(w * 32 + ci * 16 + l15) * 128 +
                                                (((s * 4 + g) ^ l15) << 3)];
          sacc[0][ci] = __builtin_amdgcn_mfma_f32_16x16x32_bf16(qf0, kf, sacc[0][ci], 0, 0, 0);
          sacc[1][ci] = __builtin_amdgcn_mfma_f32_16x16x32_bf16(qf1, kf, sacc[1][ci], 0, 0, 0);
        }
      }
    }

    // scale + causal mask (only the diagonal kt is partial)
    const bool diag = (kt == (bm >> 2));
#pragma unroll
    for (int rt = 0; rt < 2; ++rt)
#pragma unroll
      for (int ci = 0; ci < 2; ++ci)
#pragma unroll
        for (int r = 0; r < 4; ++r) {
          float v = sacc[rt][ci][r] * s2;
          if (diag) {
            const int col = kt * 128 + w * 32 + ci * 16 + l15;
            const int row = bm * 32 + rt * 16 + g * 4 + r;
            v = (col > row) ? -1e30f : v;
          }
          sacc[rt][ci][r] = v;
        }

    // ---- online softmax; rows span all 4 waves -> LDS exchange of partials
    float tm[2][4], alpha[2][4];
#pragma unroll
    for (int rt = 0; rt < 2; ++rt)
#pragma unroll
      for (int r = 0; r < 4; ++r) {
        tm[rt][r] = fmaxf(sacc[rt][0][r], sacc[rt][1][r]);
#pragma unroll
        for (int off = 1; off <= 8; off <<= 1) tm[rt][r] = fmaxf(tm[rt][r], __shfl_xor(tm[rt][r], off));
        if (l15 == 0) sredm[w][rt * 16 + g * 4 + r] = tm[rt][r];
      }
    __syncthreads();  // partial maxes visible
#pragma unroll
    for (int rt = 0; rt < 2; ++rt)
#pragma unroll
      for (int r = 0; r < 4; ++r) {
        const int row = rt * 16 + g * 4 + r;
        const float m4 = fmaxf(fmaxf(sredm[0][row], sredm[1][row]),
                               fmaxf(sredm[2][row], sredm[3][row]));
        const float mnew = fmaxf(m_r[rt][r], m4);
        alpha[rt][r] = __expf(m_r[rt][r] - mnew);
        m_r[rt][r] = mnew;
        const float p0 = __expf(sacc[rt][0][r] - mnew);
        const float p1 = __expf(sacc[rt][1][r] - mnew);
        sacc[rt][0][r] = p0; sacc[rt][1][r] = p1;
        float s = p0 + p1;
#pragma unroll
        for (int off = 1; off <= 8; off <<= 1) s += __shfl_xor(s, off);
        if (l15 == 0) sreds[w][row] = s;
      }
    __syncthreads();  // partial sums visible
#pragma unroll
    for (int rt = 0; rt < 2; ++rt) {
#pragma unroll
      for (int r = 0; r < 4; ++r) {
        const int row = rt * 16 + g * 4 + r;
        const float s4 = (sreds[0][row] + sreds[1][row]) + (sreds[2][row] + sreds[3][row]);
        l_r[rt][r] = l_r[rt][r] * alpha[rt][r] + s4;
      }
      // rescale O accumulator
#pragma unroll
      for (int t = 0; t < 8; ++t)
#pragma unroll
        for (int r = 0; r < 4; ++r) oacc[rt][t][r] *= alpha[rt][r];
      // write P (bf16) to LDS: row rt*16+g*4+r, col w*32+ci*16+l15
#pragma unroll
      for (int ci = 0; ci < 2; ++ci)
#pragma unroll
        for (int r = 0; r < 4; ++r)
          sP[(rt * 16 + g * 4 + r) * 136 + w * 32 + ci * 16 + l15] = f2b(sacc[rt][ci][r]);
    }

    // ================= Phase B: O += P @ V (32x512), output e chunked by 128
    bf16x8 pf[2][4];
    for (int ech = 0; ech < 4; ++ech) {
      __syncthreads();  // ech0: sP visible + Phase A sU reads done; else: prior vf reads done
      // stage V e-rows [ech*128,+128) x t-cols [kt*128,+128); wave-local rows
#pragma unroll
      for (int j = 0; j < 8; ++j) {
        const int c = w * 8 + j;
        const int r = c * 4 + g;
        const u16* gsrc = VT + base + (long)(ech * 128 + r) * 1024 + kt * 128 +
                          ((l15 ^ (r & 15)) << 3);
        gload_lds16(gsrc, &sU[c * 512]);
      }
      if (ech == 0) {  // P A-frags (loop-invariant): row rt*16+l15, k = ks*32+g*8
#pragma unroll
        for (int rt = 0; rt < 2; ++rt)
#pragma unroll
          for (int ks = 0; ks < 4; ++ks)
            pf[rt][ks] = *(const bf16x8*)&sP[(rt * 16 + l15) * 136 + ks * 32 + g * 8];
      }
      __syncthreads();  // DMA landed
#pragma unroll
      for (int ci = 0; ci < 2; ++ci) {
#pragma unroll
        for (int ks = 0; ks < 4; ++ks) {
          const bf16x8 vf = *(const bf16x8*)&sU[(w * 32 + ci * 16 + l15) * 128 +
                                                (((ks * 4 + g) ^ l15) << 3)];
#pragma unroll
          for (int rt = 0; rt < 2; ++rt)
            oacc[rt][ech * 2 + ci] =
                __builtin_amdgcn_mfma_f32_16x16x32_bf16(pf[rt][ks], vf, oacc[rt][ech * 2 + ci], 0, 0, 0);
        }
      }
    }
  }

  // ---- epilogue: O = oacc / l, write (b,h,t,e) bf16
#pragma unroll
  for (int rt = 0; rt < 2; ++rt) {
    float inv[4];
#pragma unroll
    for (int r = 0; r < 4; ++r) inv[r] = 1.0f / l_r[rt][r];
#pragma unroll
    for (int t = 0; t < 8; ++t) {
      const int col = (t >> 1) * 128 + w * 32 + (t & 1) * 16 + l15;
#pragma unroll
      for (int r = 0; r < 4; ++r) {
        const int row = bm * 32 + rt * 16 + g * 4 + r;
        O[base + (long)row * 512 + col] = f2b(oacc[rt][t][r] * inv[r]);
      }
    }
  }
}

extern "C" void kernel_launch(void* const* d_in, const int* in_sizes, int n_in,
                              void* d_out, int out_size, void* d_ws, size_t ws_size,
                              hipStream_t stream) {
  const float* x   = (const float*)d_in[0];
  const float* w_k = (const float*)d_in[1];
  const float* w_q = (const float*)d_in[2];
  const float* w_v = (const float*)d_in[3];
  const float* w_u = (const float*)d_in[4];
  const float* b_u = (const float*)d_in[5];
  float* out = (float*)d_out;
  char* ws = (char*)d_ws;

  const long MB = 1048576;
  // ws: xb 0, wqb 4, wkb 8, wvb 12, wub 16 (bf16); Q 20..52, K 52..84, VT 84..116, O 116..148
  u16* xb  = (u16*)(ws);
  u16* wqb = (u16*)(ws + 4 * MB);
  u16* wvb = (u16*)(ws + 12 * MB);
  u16* wub = (u16*)(ws + 16 * MB);
  u16* Q   = (u16*)(ws + 20 * MB);
  u16* Kb  = (u16*)(ws + 52 * MB);
  u16* VT  = (u16*)(ws + 84 * MB);
  u16* O   = (u16*)(ws + 116 * MB);

  const dim3 blk(256);
  const float s2 = 0.044194173824159216f;  // 512^{-1/2} == (e^{-1/4})^2 folded into scores

  // fused fp32 -> bf16 conversions: dest order matches ws layout (x,q,k,v,u)
  cvt_kernel<<<dim3(2048, 5), blk, 0, stream>>>(x, w_q, w_k, w_v, w_u, xb);

  // Q,K projections fused (z in {q,k}) -> (b,h,t,e)
  gemm_kernel<A_PLAIN, C_BF16_BHTE, false>
      <<<dim3(32, 32, 2), blk, 0, stream>>>(xb, 512, wqb, 512, 2097152,
                                            Q, 0, 16777216, 512, 1.0f);
  // V projection -> transposed (b,h,e,t)
  gemm_kernel<A_PLAIN, C_BF16_BHET, false>
      <<<dim3(32, 32, 1), blk, 0, stream>>>(xb, 512, wvb, 512, 0,
                                            VT, 0, 0, 512, 1.0f);

  // flash attention: 32 Q-tiles (32 rows each) x 32 (b,h)
  flash_kernel<<<dim3(32, 32), blk, 0, stream>>>(Q, Kb, VT, O, s2);

  // unify: out(fp32) = O2d @ w_u^T + b_u, split-K x4 (chunk 1024), atomics over bias-init
  init_out_kernel<<<2048, blk, 0, stream>>>(out, b_u);
  gemm_kernel<A_HEADBLK, C_F32_ATOMIC, true>
      <<<dim3(4, 32, 4), blk, 0, stream>>>(O, 0, wub, 4096, 0, out, 512, 0, 1024, 1.0f);
}